// Round 6
// baseline (275.173 us; speedup 1.0000x reference)
//
#include <hip/hip_runtime.h>

// ---------------------------------------------------------------------------
// ConvFeatureExtractor: profile = rownorm( freq @ softmax(matches/T, axis=1)^T )
//   matches[f,i] = Thi[f, i>>6] + Tlo[f, i&63]  (separable!), F=8192, M=4096,
//   B=1024, K=6.  =>  probs[f,i] = e1[f,i>>6] * e2[f,i&63],  Z = (sum e1)(sum e2).
// R12: kill the norm kernel + its launch. gemm = R10's proven loop (72 us,
//   best) + fused normalization: per-block row partials -> atomicAdd into
//   rowsum[1024]; grid = 1024 blocks @ 4/CU ALL CO-RESIDENT (launch_bounds
//   (256,4), 56 VGPR, 24KB LDS) -> global spin barrier is deadlock-free
//   (gemm runs alone, stream-ordered); then scale acc in-register by
//   1/rowsum and write C ONCE. C never re-read. prep zeros rowsum/cnt each
//   run (replay-safe). R11 lesson: no-LDS direct-load gemm is latency-bound
//   (17% MfmaUtil) -- LDS staging earns its barriers; reverted.
// ---------------------------------------------------------------------------

typedef __bf16  bf16x8 __attribute__((ext_vector_type(8)));
typedef float   f32x4  __attribute__((ext_vector_type(4)));

#define GLD16(gp, lp)                                                          \
  __builtin_amdgcn_global_load_lds(                                            \
      (const __attribute__((address_space(1))) void*)(gp),                     \
      (__attribute__((address_space(3))) void*)(lp), 16, 0, 0)

#define NBLK 1024

__device__ __forceinline__ short f2bf(float x) {
  unsigned u = __float_as_uint(x);
  unsigned r = (u + 0x7fffu + ((u >> 16) & 1u)) >> 16;   // RNE
  return (short)r;
}

__device__ __forceinline__ float wave_max(float v) {
  #pragma unroll
  for (int off = 32; off; off >>= 1) v = fmaxf(v, __shfl_xor(v, off, 64));
  return v;
}
__device__ __forceinline__ float wave_sum(float v) {
  #pragma unroll
  for (int off = 32; off; off >>= 1) v += __shfl_xor(v, off, 64);
  return v;
}

// ---------------- k1: prep = cast (blocks 0..4095) + tables (4096..6143) ----
// Also zeroes rowsum[1024] + cnt (block 0) for the fused-norm gemm.
__global__ __launch_bounds__(256) void prep_kernel(const float* __restrict__ freq,
                                                   short* __restrict__ freqb,
                                                   const float* __restrict__ kp,
                                                   const float* __restrict__ temp,
                                                   float* __restrict__ E1t,
                                                   float* __restrict__ E2,
                                                   float* __restrict__ rowsum,
                                                   int* __restrict__ cnt) {
  if (blockIdx.x < 4096) {
    int idx = blockIdx.x * 256 + threadIdx.x;
    float4 v = ((const float4*)freq)[idx];
    short4 o;
    o.x = f2bf(v.x); o.y = f2bf(v.y); o.z = f2bf(v.z); o.w = f2bf(v.w);
    ((short4*)freqb)[idx] = o;
    if (blockIdx.x == 0) {                       // zero accumulators (replay-safe)
      ((float4*)rowsum)[threadIdx.x] = (float4){0.f, 0.f, 0.f, 0.f};
      if (threadIdx.x == 0) *cnt = 0;
    }
  } else {
    const int t = threadIdx.x;
    const int lane = t & 63, wave = t >> 6;
    const int f = (blockIdx.x - 4096) * 4 + wave;
    const float* P = kp + f * 24;
    const int d0 = (lane >> 4) & 3, d1 = (lane >> 2) & 3, d2 = lane & 3;
    const float thi = P[d0 * 6 + 0] + P[d1 * 6 + 1] + P[d2 * 6 + 2];
    const float tlo = P[d0 * 6 + 3] + P[d1 * 6 + 4] + P[d2 * 6 + 5];
    const float mxhi = wave_max(thi), mxlo = wave_max(tlo);
    const float invT = 1.0f / temp[0];
    const float e1 = __expf((thi - mxhi) * invT);
    const float e2 = __expf((tlo - mxlo) * invT);
    const float s1 = wave_sum(e1), s2 = wave_sum(e2);
    const float invZ = 1.0f / (s1 * s2);
    E1t[lane * 8192 + f] = e1 * invZ;
    E2[(size_t)f * 64 + lane] = e2;
  }
}

// ---------------- k2: GEMM + fused row-normalization ----------------
// TM=64, TN=128, BK=64; grid 1024 blocks (4/CU, all resident), 4 waves 1Mx4N.
// Loop identical to R10: XCD remap, 3-deep 8KB A buffers, 1 barrier/kt,
// counted vmcnt(4), re-associated e1 fold (MFMA on constant e2 frags).
// Epilogue: rowsum atomics -> grid spin barrier -> scale acc -> single C write.
__global__ __launch_bounds__(256, 4) void gemm_kernel(const short* __restrict__ A,
                                                      const float* __restrict__ E1t,
                                                      const float* __restrict__ E2,
                                                      float* __restrict__ C,
                                                      float* __restrict__ rowsum,
                                                      int* __restrict__ cnt) {
  __shared__ short As[3][64 * 64];               // 3 x 8 KiB rotating buffers

  const int t = threadIdx.x;
  const int lane = t & 63, wave = t >> 6;
  const int quad = lane >> 4, l16 = lane & 15;

  // XCD-aware remap: d = dispatch order; XCD k = d%8 owns L in [128k,128k+128)
  // = m-strips {2k,2k+1} (A slice 1MB, L2-hot).
  const int d  = blockIdx.y * 64 + blockIdx.x;
  const int L  = (d & 7) * 128 + (d >> 3);
  const int m0 = (L >> 6) * 64;                  // batch tile (16 strips)
  const int n0 = (L & 63) * 128;                 // filter tile (64 strips)
  const int wn = wave * 32;                      // wave's n-offset

  f32x4 acc[4][2];
  #pragma unroll
  for (int i = 0; i < 4; i++)
    #pragma unroll
    for (int j = 0; j < 2; j++) acc[i][j] = (f32x4){0.f, 0.f, 0.f, 0.f};

  // constant bf16 e2 fragments: lane (l16,quad) of frag (ks,j) covers
  // k = (ks*4+quad)*8 + 0..7 for filter row nrow[j]
  int nrow[2];
  #pragma unroll
  for (int j = 0; j < 2; j++) nrow[j] = n0 + wn + j * 16 + l16;
  bf16x8 e2f[2][2];
  #pragma unroll
  for (int j = 0; j < 2; j++)
    #pragma unroll
    for (int ks = 0; ks < 2; ks++) {
      const float* p = E2 + (size_t)nrow[j] * 64 + (ks * 4 + quad) * 8;
      float4 lo = *(const float4*)p, hi = *(const float4*)(p + 4);
      bf16x8 bb;
      bb[0] = (__bf16)lo.x; bb[1] = (__bf16)lo.y;
      bb[2] = (__bf16)lo.z; bb[3] = (__bf16)lo.w;
      bb[4] = (__bf16)hi.x; bb[5] = (__bf16)hi.y;
      bb[6] = (__bf16)hi.z; bb[7] = (__bf16)hi.w;
      e2f[ks][j] = bb;
    }

  const int lane_row = lane >> 3;                      // 0..7 within 8-row chunk
  const int src_col = ((lane & 7) ^ lane_row) * 8;     // swizzled global col (shorts)
  const int sw = l16 & 7;                              // reader swizzle key (= row&7)
  const int chunk = wave * 2;                          // wave stages chunks 2w, 2w+1
  const short* Abase = A + (size_t)(m0 + lane_row) * 4096 + src_col;

  #define STG(kt, buf) do {                                                    \
    GLD16(Abase + (size_t)((chunk + 0) * 8) * 4096 + (kt) * 64,                \
          &As[buf][(chunk + 0) * 512 + lane * 8]);                             \
    GLD16(Abase + (size_t)((chunk + 1) * 8) * 4096 + (kt) * 64,                \
          &As[buf][(chunk + 1) * 512 + lane * 8]);                             \
  } while (0)

  // prologue: S(0), e1(0), S(1)  -> 6 VMEM outstanding
  STG(0, 0);
  float e1n[2], e1c[2];
  #pragma unroll
  for (int j = 0; j < 2; j++) e1n[j] = E1t[nrow[j]];
  STG(1, 1);

  const f32x4 Z4 = (f32x4){0.f, 0.f, 0.f, 0.f};

  #pragma unroll 1
  for (int kt = 0; kt < 64; ++kt) {
    const int cb = kt % 3;
    const int sb = (kt + 2) % 3;
    const int tn = (kt + 1 > 63) ? 63 : kt + 1;        // tail: dummy reload
    const int ts = (kt + 2 > 63) ? 63 : kt + 2;        // tail: dummy restage

    asm volatile("s_waitcnt vmcnt(4)" ::: "memory");   // S(kt) landed
    __builtin_amdgcn_s_barrier();                      // publish tile kt

    bf16x8 a[4][2];
    #pragma unroll
    for (int i = 0; i < 4; i++)
      #pragma unroll
      for (int ks = 0; ks < 2; ks++)
        a[i][ks] = *(const bf16x8*)&As[cb][(i * 16 + l16) * 64 +
                                          (((ks * 4 + quad) ^ sw) * 8)];

    #pragma unroll
    for (int j = 0; j < 2; j++) e1c[j] = e1n[j];
    #pragma unroll
    for (int j = 0; j < 2; j++) e1n[j] = E1t[tn * 8192 + nrow[j]];  // +2 VMEM
    STG(ts, sb);                                                    // +2 VMEM

    __builtin_amdgcn_s_setprio(1);
    #pragma unroll
    for (int j = 0; j < 2; j++) {
      const f32x4 s4 = (f32x4){e1c[j], e1c[j], e1c[j], e1c[j]};
      #pragma unroll
      for (int i = 0; i < 4; i++) {
        f32x4 P = __builtin_amdgcn_mfma_f32_16x16x32_bf16(a[i][0], e2f[0][j], Z4, 0, 0, 0);
        P = __builtin_amdgcn_mfma_f32_16x16x32_bf16(a[i][1], e2f[1][j], P, 0, 0, 0);
        acc[i][j] += s4 * P;                           // f32 fold of e1
      }
    }
    __builtin_amdgcn_s_setprio(0);
    // no bottom barrier: restage target (kt+2)%3 last read at kt-1, ordered
    // by this kt's top barrier.
  }

  asm volatile("s_waitcnt vmcnt(0)" ::: "memory");     // drain tail dummies

  // ---- fused normalization ----
  // (1) per-row partials over this block's 128 cols: lane holds 2 cols (j) of
  // row i*16+quad*4+r; butterfly over l16 (16 lanes, same row, cols wn+j*16+l16).
  float rs[4][4];
  #pragma unroll
  for (int i = 0; i < 4; i++)
    #pragma unroll
    for (int r = 0; r < 4; r++) {
      float p = acc[i][0][r] + acc[i][1][r];
      #pragma unroll
      for (int off = 1; off < 16; off <<= 1) p += __shfl_xor(p, off, 64);
      rs[i][r] = p;
    }
  if (l16 == 0) {
    #pragma unroll
    for (int i = 0; i < 4; i++)
      #pragma unroll
      for (int r = 0; r < 4; r++)
        atomicAdd(&rowsum[m0 + i * 16 + quad * 4 + r], rs[i][r]);
  }

  // (2) grid barrier: all 1024 blocks co-resident (4/CU by launch_bounds).
  __syncthreads();                               // drains vmcnt -> atomics done
  if (t == 0) {
    atomicAdd(cnt, 1);
    while (__hip_atomic_load(cnt, __ATOMIC_RELAXED, __HIP_MEMORY_SCOPE_AGENT) < NBLK)
      __builtin_amdgcn_s_sleep(8);
  }
  __syncthreads();
  __threadfence();                               // acquire: rowsum now final

  // (3) scale in-register and write C once. row = m0+i*16+quad*4+r.
  #pragma unroll
  for (int i = 0; i < 4; i++) {
    #pragma unroll
    for (int r = 0; r < 4; r++) {
      const int brow = m0 + i * 16 + quad * 4 + r;
      const float inv = 1.0f / rowsum[brow];
      float* crow = C + (size_t)brow * 8192 + n0 + wn + l16;
      #pragma unroll
      for (int j = 0; j < 2; j++) crow[j * 16] = acc[i][j][r] * inv;
    }
  }
  #undef STG
}

// ---------------------------------------------------------------------------
extern "C" void kernel_launch(void* const* d_in, const int* in_sizes, int n_in,
                              void* d_out, int out_size, void* d_ws, size_t ws_size,
                              hipStream_t stream) {
  const float* freq    = (const float*)d_in[0];   // 1024*4096
  const float* kparams = (const float*)d_in[1];   // 8192*4*6
  const float* temp    = (const float*)d_in[2];   // 1
  // d_in[3] = kmer_idcs (recomputed analytically in-kernel)

  float* out = (float*)d_out;                     // 1024*8192 f32

  short* freqb  = (short*)d_ws;                   // 1024*4096 bf16 = 8 MiB
  float* E1t    = (float*)(freqb + (size_t)1024 * 4096);  // 64*8192 f32 = 2 MiB
  float* E2     = E1t + (size_t)64 * 8192;                // 8192*64 f32 = 2 MiB
  float* rowsum = E2 + (size_t)8192 * 64;                 // 1024 f32
  int*   cnt    = (int*)(rowsum + 1024);                  // 1

  prep_kernel<<<6144, 256, 0, stream>>>(freq, freqb, kparams, temp, E1t, E2,
                                        rowsum, cnt);
  gemm_kernel<<<dim3(64, 16), 256, 0, stream>>>(freqb, E1t, E2, out, rowsum, cnt);
}

// Round 7
// 197.069 us; speedup vs baseline: 1.3963x; 1.3963x over previous
//
#include <hip/hip_runtime.h>

// ---------------------------------------------------------------------------
// ConvFeatureExtractor: profile = rownorm( freq @ softmax(matches/T, axis=1)^T )
//   matches[f,i] = Thi[f, i>>6] + Tlo[f, i&63]  (separable!), F=8192, M=4096,
//   B=1024, K=6.  =>  probs[f,i] = e1[f,i>>6] * e2[f,i&63],  Z = (sum e1)(sum e2).
// R13: block-local analytic normalization (no norm kernel, no grid sync).
//   rowsum[b] = sum_i freq[b,i] * cp[i],  cp[hi][lo] = sum_f e1'[f,hi]e2[f,lo].
//   cpk (64 blocks) computes cp (f32 atomics into 16KB); gemm = R10's proven
//   loop + per-kt 8 broadcast-B MFMAs (B-frag = cp[kt] slice, l16-independent
//   -> every D column = rowsum partial) accumulating full-row denominators
//   IN REGISTER; epilogue scales acc by 1/acc_rs and writes C once.
//   R12 lesson: grid spin barrier = straggler catastrophe (212us). Reverted.
//   Launches: prep (cast+tables+zero), cpk, gemm  (R10 had 4).
// ---------------------------------------------------------------------------

typedef __bf16  bf16x8 __attribute__((ext_vector_type(8)));
typedef __bf16  bf16x4 __attribute__((ext_vector_type(4)));
typedef float   f32x4  __attribute__((ext_vector_type(4)));

#define GLD16(gp, lp)                                                          \
  __builtin_amdgcn_global_load_lds(                                            \
      (const __attribute__((address_space(1))) void*)(gp),                     \
      (__attribute__((address_space(3))) void*)(lp), 16, 0, 0)

__device__ __forceinline__ short f2bf(float x) {
  unsigned u = __float_as_uint(x);
  unsigned r = (u + 0x7fffu + ((u >> 16) & 1u)) >> 16;   // RNE
  return (short)r;
}

__device__ __forceinline__ float wave_max(float v) {
  #pragma unroll
  for (int off = 32; off; off >>= 1) v = fmaxf(v, __shfl_xor(v, off, 64));
  return v;
}
__device__ __forceinline__ float wave_sum(float v) {
  #pragma unroll
  for (int off = 32; off; off >>= 1) v += __shfl_xor(v, off, 64);
  return v;
}

// ---------------- k1: prep = cast (blocks 0..4095) + tables (4096..6143) ----
// Block 0 also zeroes cpf[4096] (f32 accumulation target; replay-safe).
__global__ __launch_bounds__(256) void prep_kernel(const float* __restrict__ freq,
                                                   short* __restrict__ freqb,
                                                   const float* __restrict__ kp,
                                                   const float* __restrict__ temp,
                                                   float* __restrict__ E1t,
                                                   float* __restrict__ E2,
                                                   float* __restrict__ cpf) {
  if (blockIdx.x < 4096) {
    int idx = blockIdx.x * 256 + threadIdx.x;
    float4 v = ((const float4*)freq)[idx];
    short4 o;
    o.x = f2bf(v.x); o.y = f2bf(v.y); o.z = f2bf(v.z); o.w = f2bf(v.w);
    ((short4*)freqb)[idx] = o;
    if (blockIdx.x == 0) {                       // zero cp accumulator (16 KB)
      #pragma unroll
      for (int x = 0; x < 4; x++)
        ((float4*)cpf)[threadIdx.x * 4 + x] = (float4){0.f, 0.f, 0.f, 0.f};
    }
  } else {
    const int t = threadIdx.x;
    const int lane = t & 63, wave = t >> 6;
    const int f = (blockIdx.x - 4096) * 4 + wave;
    const float* P = kp + f * 24;
    const int d0 = (lane >> 4) & 3, d1 = (lane >> 2) & 3, d2 = lane & 3;
    const float thi = P[d0 * 6 + 0] + P[d1 * 6 + 1] + P[d2 * 6 + 2];
    const float tlo = P[d0 * 6 + 3] + P[d1 * 6 + 4] + P[d2 * 6 + 5];
    const float mxhi = wave_max(thi), mxlo = wave_max(tlo);
    const float invT = 1.0f / temp[0];
    const float e1 = __expf((thi - mxhi) * invT);
    const float e2 = __expf((tlo - mxlo) * invT);
    const float s1 = wave_sum(e1), s2 = wave_sum(e2);
    const float invZ = 1.0f / (s1 * s2);
    E1t[lane * 8192 + f] = e1 * invZ;
    E2[(size_t)f * 64 + lane] = e2;
  }
}

// ---------------- k2: cpk -- cp[hi][lo] = sum_f E1t[hi][f] * E2[f][lo] ------
// 64 blocks, each a 128-filter chunk: stage E1/E2 chunks in LDS, each thread
// accumulates 16 (hi,lo) entries over 128 f, then f32 atomicAdd into cpf.
__global__ __launch_bounds__(256) void cp_kernel(const float* __restrict__ E1t,
                                                 const float* __restrict__ E2,
                                                 float* __restrict__ cpf) {
  __shared__ float E1s[64 * 129];                // padded: bank-spread e1 reads
  __shared__ float E2s[128 * 64];
  const int t = threadIdx.x;
  const int F0 = blockIdx.x * 128;

  #pragma unroll
  for (int r = 0; r < 32; r++) {                 // stage E1 chunk [64 hi][128 f]
    int idx = r * 256 + t;
    E1s[(idx >> 7) * 129 + (idx & 127)] = E1t[(idx >> 7) * 8192 + F0 + (idx & 127)];
  }
  #pragma unroll
  for (int r = 0; r < 32; r++) {                 // stage E2 chunk [128 f][64 lo]
    int idx = r * 256 + t;
    E2s[idx] = E2[(size_t)(F0 + (idx >> 6)) * 64 + (idx & 63)];
  }
  __syncthreads();

  const int hi = t >> 2, lo0 = (t & 3) * 16;     // thread owns cp[hi][lo0..lo0+16)
  float a[16];
  #pragma unroll
  for (int x = 0; x < 16; x++) a[x] = 0.f;

  #pragma unroll 2
  for (int ff = 0; ff < 128; ff++) {
    const float e1v = E1s[hi * 129 + ff];
    const float4* p = (const float4*)&E2s[ff * 64 + lo0];
    float4 v0 = p[0], v1 = p[1], v2 = p[2], v3 = p[3];
    a[0]  += e1v * v0.x; a[1]  += e1v * v0.y; a[2]  += e1v * v0.z; a[3]  += e1v * v0.w;
    a[4]  += e1v * v1.x; a[5]  += e1v * v1.y; a[6]  += e1v * v1.z; a[7]  += e1v * v1.w;
    a[8]  += e1v * v2.x; a[9]  += e1v * v2.y; a[10] += e1v * v2.z; a[11] += e1v * v2.w;
    a[12] += e1v * v3.x; a[13] += e1v * v3.y; a[14] += e1v * v3.z; a[15] += e1v * v3.w;
  }
  #pragma unroll
  for (int x = 0; x < 16; x++) atomicAdd(&cpf[hi * 64 + lo0 + x], a[x]);
}

// ---------------- k3: GEMM + local normalization ----------------
// TM=64, TN=128, BK=64; grid 1024 blocks (4/CU), 4 waves 1Mx4N (wave 64x32).
// Loop = R10 (XCD remap, 3-deep 8KB A buffers, 1 barrier/kt, vmcnt(4),
// re-associated e1 fold) + per-kt rowsum MFMAs vs broadcast cp fragment.
__global__ __launch_bounds__(256, 4) void gemm_kernel(const short* __restrict__ A,
                                                      const float* __restrict__ E1t,
                                                      const float* __restrict__ E2,
                                                      const float* __restrict__ cpf,
                                                      float* __restrict__ C) {
  __shared__ short As[3][64 * 64];               // 3 x 8 KiB rotating buffers
  __shared__ short cpb[64 * 64];                 // bf16 cp [kt][lo], 8 KiB

  const int t = threadIdx.x;
  const int lane = t & 63, wave = t >> 6;
  const int quad = lane >> 4, l16 = lane & 15;

  // XCD-aware remap: XCD k = d%8 owns L in [128k,128k+128) = m-strips {2k,2k+1}.
  const int d  = blockIdx.y * 64 + blockIdx.x;
  const int L  = (d & 7) * 128 + (d >> 3);
  const int m0 = (L >> 6) * 64;                  // batch tile
  const int n0 = (L & 63) * 128;                 // filter tile
  const int wn = wave * 32;                      // wave's n-offset

  // prologue A: cp f32 -> bf16 LDS table (before any STG; synced once)
  #pragma unroll
  for (int x = 0; x < 4; x++) {
    float4 c = ((const float4*)cpf)[t * 4 + x];
    bf16x4 bv = { (__bf16)c.x, (__bf16)c.y, (__bf16)c.z, (__bf16)c.w };
    *(bf16x4*)&cpb[t * 16 + x * 4] = bv;
  }
  __syncthreads();                               // cpb visible; vm/lgkm drained

  f32x4 acc[4][2];
  #pragma unroll
  for (int i = 0; i < 4; i++)
    #pragma unroll
    for (int j = 0; j < 2; j++) acc[i][j] = (f32x4){0.f, 0.f, 0.f, 0.f};
  f32x4 acc_rs[4];                               // rowsum accumulators
  #pragma unroll
  for (int i = 0; i < 4; i++) acc_rs[i] = (f32x4){0.f, 0.f, 0.f, 0.f};

  // constant bf16 e2 fragments: lane (l16,quad) of frag (ks,j) covers
  // k = (ks*4+quad)*8 + 0..7 for filter row nrow[j]
  int nrow[2];
  #pragma unroll
  for (int j = 0; j < 2; j++) nrow[j] = n0 + wn + j * 16 + l16;
  bf16x8 e2f[2][2];
  #pragma unroll
  for (int j = 0; j < 2; j++)
    #pragma unroll
    for (int ks = 0; ks < 2; ks++) {
      const float* p = E2 + (size_t)nrow[j] * 64 + (ks * 4 + quad) * 8;
      float4 lo = *(const float4*)p, hi = *(const float4*)(p + 4);
      bf16x8 bb;
      bb[0] = (__bf16)lo.x; bb[1] = (__bf16)lo.y;
      bb[2] = (__bf16)lo.z; bb[3] = (__bf16)lo.w;
      bb[4] = (__bf16)hi.x; bb[5] = (__bf16)hi.y;
      bb[6] = (__bf16)hi.z; bb[7] = (__bf16)hi.w;
      e2f[ks][j] = bb;
    }

  const int lane_row = lane >> 3;                      // 0..7 within 8-row chunk
  const int src_col = ((lane & 7) ^ lane_row) * 8;     // swizzled global col (shorts)
  const int sw = l16 & 7;                              // reader swizzle key (= row&7)
  const int chunk = wave * 2;                          // wave stages chunks 2w, 2w+1
  const short* Abase = A + (size_t)(m0 + lane_row) * 4096 + src_col;

  #define STG(kt, buf) do {                                                    \
    GLD16(Abase + (size_t)((chunk + 0) * 8) * 4096 + (kt) * 64,                \
          &As[buf][(chunk + 0) * 512 + lane * 8]);                             \
    GLD16(Abase + (size_t)((chunk + 1) * 8) * 4096 + (kt) * 64,                \
          &As[buf][(chunk + 1) * 512 + lane * 8]);                             \
  } while (0)

  // prologue B: S(0), e1(0), S(1)  -> 6 VMEM outstanding
  STG(0, 0);
  float e1n[2], e1c[2];
  #pragma unroll
  for (int j = 0; j < 2; j++) e1n[j] = E1t[nrow[j]];
  STG(1, 1);

  const f32x4 Z4 = (f32x4){0.f, 0.f, 0.f, 0.f};

  #pragma unroll 1
  for (int kt = 0; kt < 64; ++kt) {
    const int cb = kt % 3;
    const int sb = (kt + 2) % 3;
    const int tn = (kt + 1 > 63) ? 63 : kt + 1;        // tail: dummy reload
    const int ts = (kt + 2 > 63) ? 63 : kt + 2;        // tail: dummy restage

    asm volatile("s_waitcnt vmcnt(4)" ::: "memory");   // S(kt) landed
    __builtin_amdgcn_s_barrier();                      // publish tile kt

    bf16x8 a[4][2];
    #pragma unroll
    for (int i = 0; i < 4; i++)
      #pragma unroll
      for (int ks = 0; ks < 2; ks++)
        a[i][ks] = *(const bf16x8*)&As[cb][(i * 16 + l16) * 64 +
                                          (((ks * 4 + quad) ^ sw) * 8)];
    // broadcast cp fragment for this kt (l16-independent -> D cols all equal)
    bf16x8 cpv[2];
    #pragma unroll
    for (int ks = 0; ks < 2; ks++)
      cpv[ks] = *(const bf16x8*)&cpb[kt * 64 + (ks * 4 + quad) * 8];

    #pragma unroll
    for (int j = 0; j < 2; j++) e1c[j] = e1n[j];
    #pragma unroll
    for (int j = 0; j < 2; j++) e1n[j] = E1t[tn * 8192 + nrow[j]];  // +2 VMEM
    STG(ts, sb);                                                    // +2 VMEM

    __builtin_amdgcn_s_setprio(1);
    #pragma unroll
    for (int j = 0; j < 2; j++) {
      const f32x4 s4 = (f32x4){e1c[j], e1c[j], e1c[j], e1c[j]};
      #pragma unroll
      for (int i = 0; i < 4; i++) {
        f32x4 P = __builtin_amdgcn_mfma_f32_16x16x32_bf16(a[i][0], e2f[0][j], Z4, 0, 0, 0);
        P = __builtin_amdgcn_mfma_f32_16x16x32_bf16(a[i][1], e2f[1][j], P, 0, 0, 0);
        acc[i][j] += s4 * P;                           // f32 fold of e1
      }
    }
    // rowsum partials: 8 MFMA vs broadcast cp (includes e1' via cp definition)
    #pragma unroll
    for (int i = 0; i < 4; i++) {
      acc_rs[i] = __builtin_amdgcn_mfma_f32_16x16x32_bf16(a[i][0], cpv[0], acc_rs[i], 0, 0, 0);
      acc_rs[i] = __builtin_amdgcn_mfma_f32_16x16x32_bf16(a[i][1], cpv[1], acc_rs[i], 0, 0, 0);
    }
    __builtin_amdgcn_s_setprio(0);
    // no bottom barrier: restage target (kt+2)%3 last read at kt-1, ordered
    // by this kt's top barrier.
  }

  asm volatile("s_waitcnt vmcnt(0)" ::: "memory");     // drain tail dummies

  // epilogue: local normalization. acc_rs[i][r] = full rowsum of row
  // m0+i*16+quad*4+r (identical in every lane/block: same bf16 inputs, same
  // MFMA order). C/D layout col=lane&15, row=quad*4+reg.
  #pragma unroll
  for (int i = 0; i < 4; i++) {
    #pragma unroll
    for (int r = 0; r < 4; r++) {
      const int brow = m0 + i * 16 + quad * 4 + r;
      const float inv = 1.0f / acc_rs[i][r];
      float* crow = C + (size_t)brow * 8192 + n0 + wn + l16;
      #pragma unroll
      for (int j = 0; j < 2; j++) crow[j * 16] = acc[i][j][r] * inv;
    }
  }
  #undef STG
}

// ---------------------------------------------------------------------------
extern "C" void kernel_launch(void* const* d_in, const int* in_sizes, int n_in,
                              void* d_out, int out_size, void* d_ws, size_t ws_size,
                              hipStream_t stream) {
  const float* freq    = (const float*)d_in[0];   // 1024*4096
  const float* kparams = (const float*)d_in[1];   // 8192*4*6
  const float* temp    = (const float*)d_in[2];   // 1
  // d_in[3] = kmer_idcs (recomputed analytically in-kernel)

  float* out = (float*)d_out;                     // 1024*8192 f32

  short* freqb = (short*)d_ws;                    // 1024*4096 bf16 = 8 MiB
  float* E1t   = (float*)(freqb + (size_t)1024 * 4096);  // 64*8192 f32 = 2 MiB
  float* E2    = E1t + (size_t)64 * 8192;                // 8192*64 f32 = 2 MiB
  float* cpf   = E2 + (size_t)8192 * 64;                 // 4096 f32 = 16 KiB

  prep_kernel<<<6144, 256, 0, stream>>>(freq, freqb, kparams, temp, E1t, E2, cpf);
  cp_kernel  <<<64, 256, 0, stream>>>(E1t, E2, cpf);
  gemm_kernel<<<dim3(64, 16), 256, 0, stream>>>(freqb, E1t, E2, cpf, out);
}

// Round 8
// 157.561 us; speedup vs baseline: 1.7465x; 1.2508x over previous
//
#include <hip/hip_runtime.h>

// ---------------------------------------------------------------------------
// ConvFeatureExtractor: profile = rownorm( freq @ softmax(matches/T, axis=1)^T )
//   matches[f,i] = Thi[f, i>>6] + Tlo[f, i&63]  (separable!), F=8192, M=4096,
//   B=1024, K=6.  =>  probs[f,i] = e1[f,i>>6] * e2[f,i&63],  Z = (sum e1)(sum e2).
// R14: convoy decorrelation on the proven R10 gemm (72us, MfmaUtil 39%).
//   Theory: 4 co-resident blocks march in kt-lockstep (identical code, same
//   launch) -> all waves on a SIMD hit their {vmcnt,barrier,ds-chain} phase
//   together, starving the MFMA pipe (~60% idle). K-sum is order-independent,
//   so each block processes physical tiles kk=(kt+phase)&63 with
//   phase = ((d>>3)&3)*16 -> co-resident blocks offset by 16 kts; one block's
//   MFMA burst covers another's ds/barrier phase. Zero extra work/sync.
//   R13 lessons: analytic cp-normalization net-negative (extra MFMAs beat the
//   norm kernel they replace); grid barriers catastrophic (R12). Plain norm
//   kernel restored; prep = merged cast+tables (R11, fewer launches).
// ---------------------------------------------------------------------------

typedef __bf16  bf16x8 __attribute__((ext_vector_type(8)));
typedef float   f32x4  __attribute__((ext_vector_type(4)));

#define GLD16(gp, lp)                                                          \
  __builtin_amdgcn_global_load_lds(                                            \
      (const __attribute__((address_space(1))) void*)(gp),                     \
      (__attribute__((address_space(3))) void*)(lp), 16, 0, 0)

__device__ __forceinline__ short f2bf(float x) {
  unsigned u = __float_as_uint(x);
  unsigned r = (u + 0x7fffu + ((u >> 16) & 1u)) >> 16;   // RNE
  return (short)r;
}

__device__ __forceinline__ float wave_max(float v) {
  #pragma unroll
  for (int off = 32; off; off >>= 1) v = fmaxf(v, __shfl_xor(v, off, 64));
  return v;
}
__device__ __forceinline__ float wave_sum(float v) {
  #pragma unroll
  for (int off = 32; off; off >>= 1) v += __shfl_xor(v, off, 64);
  return v;
}

// ---------------- k1: prep = cast (blocks 0..4095) + tables (4096..6143) ----
__global__ __launch_bounds__(256) void prep_kernel(const float* __restrict__ freq,
                                                   short* __restrict__ freqb,
                                                   const float* __restrict__ kp,
                                                   const float* __restrict__ temp,
                                                   float* __restrict__ E1t,
                                                   float* __restrict__ E2) {
  if (blockIdx.x < 4096) {
    int idx = blockIdx.x * 256 + threadIdx.x;
    float4 v = ((const float4*)freq)[idx];
    short4 o;
    o.x = f2bf(v.x); o.y = f2bf(v.y); o.z = f2bf(v.z); o.w = f2bf(v.w);
    ((short4*)freqb)[idx] = o;
  } else {
    const int t = threadIdx.x;
    const int lane = t & 63, wave = t >> 6;
    const int f = (blockIdx.x - 4096) * 4 + wave;
    const float* P = kp + f * 24;
    const int d0 = (lane >> 4) & 3, d1 = (lane >> 2) & 3, d2 = lane & 3;
    const float thi = P[d0 * 6 + 0] + P[d1 * 6 + 1] + P[d2 * 6 + 2];
    const float tlo = P[d0 * 6 + 3] + P[d1 * 6 + 4] + P[d2 * 6 + 5];
    const float mxhi = wave_max(thi), mxlo = wave_max(tlo);
    const float invT = 1.0f / temp[0];
    const float e1 = __expf((thi - mxhi) * invT);
    const float e2 = __expf((tlo - mxlo) * invT);
    const float s1 = wave_sum(e1), s2 = wave_sum(e2);
    const float invZ = 1.0f / (s1 * s2);
    E1t[lane * 8192 + f] = e1 * invZ;
    E2[(size_t)f * 64 + lane] = e2;
  }
}

// ---------------- k2: GEMM pooled = A(1024x4096) * B^T, B[f,i]=e1[f,i>>6]e2[f,i&63]
// TM=64, TN=128, BK=64; grid 1024 blocks (4/CU), 4 waves 1Mx4N (wave 64x32).
// R10 loop (XCD remap, 3-deep 8KB A buffers, 1 barrier/kt, counted vmcnt(4),
// re-associated e1 fold) + per-block kt-phase rotation (convoy decorrelation).
__global__ __launch_bounds__(256, 4) void gemm_kernel(const short* __restrict__ A,
                                                      const float* __restrict__ E1t,
                                                      const float* __restrict__ E2,
                                                      float* __restrict__ C) {
  __shared__ short As[3][64 * 64];               // 3 x 8 KiB rotating buffers

  const int t = threadIdx.x;
  const int lane = t & 63, wave = t >> 6;
  const int quad = lane >> 4, l16 = lane & 15;

  // XCD-aware remap: d = dispatch order; XCD k = d%8 owns L in [128k,128k+128)
  // = m-strips {2k,2k+1} (A slice 1MB, L2-hot).
  const int d  = blockIdx.y * 64 + blockIdx.x;
  const int L  = (d & 7) * 128 + (d >> 3);
  const int m0 = (L >> 6) * 64;                  // batch tile (16 strips)
  const int n0 = (L & 63) * 128;                 // filter tile (64 strips)
  const int wn = wave * 32;                      // wave's n-offset

  // convoy decorrelation: co-resident blocks (consecutive d>>3 at fixed d&7)
  // start 16 k-tiles apart. K-sum is order-independent.
  const int phase = ((d >> 3) & 3) << 4;

  f32x4 acc[4][2];
  #pragma unroll
  for (int i = 0; i < 4; i++)
    #pragma unroll
    for (int j = 0; j < 2; j++) acc[i][j] = (f32x4){0.f, 0.f, 0.f, 0.f};

  // constant bf16 e2 fragments: lane (l16,quad) of frag (ks,j) covers
  // k = (ks*4+quad)*8 + 0..7 for filter row nrow[j]
  int nrow[2];
  #pragma unroll
  for (int j = 0; j < 2; j++) nrow[j] = n0 + wn + j * 16 + l16;
  bf16x8 e2f[2][2];
  #pragma unroll
  for (int j = 0; j < 2; j++)
    #pragma unroll
    for (int ks = 0; ks < 2; ks++) {
      const float* p = E2 + (size_t)nrow[j] * 64 + (ks * 4 + quad) * 8;
      float4 lo = *(const float4*)p, hi = *(const float4*)(p + 4);
      bf16x8 bb;
      bb[0] = (__bf16)lo.x; bb[1] = (__bf16)lo.y;
      bb[2] = (__bf16)lo.z; bb[3] = (__bf16)lo.w;
      bb[4] = (__bf16)hi.x; bb[5] = (__bf16)hi.y;
      bb[6] = (__bf16)hi.z; bb[7] = (__bf16)hi.w;
      e2f[ks][j] = bb;
    }

  const int lane_row = lane >> 3;                      // 0..7 within 8-row chunk
  const int src_col = ((lane & 7) ^ lane_row) * 8;     // swizzled global col (shorts)
  const int sw = l16 & 7;                              // reader swizzle key (= row&7)
  const int chunk = wave * 2;                          // wave stages chunks 2w, 2w+1
  const short* Abase = A + (size_t)(m0 + lane_row) * 4096 + src_col;

  #define STG(kp_, buf) do {                                                   \
    GLD16(Abase + (size_t)((chunk + 0) * 8) * 4096 + (kp_) * 64,               \
          &As[buf][(chunk + 0) * 512 + lane * 8]);                             \
    GLD16(Abase + (size_t)((chunk + 1) * 8) * 4096 + (kp_) * 64,               \
          &As[buf][(chunk + 1) * 512 + lane * 8]);                             \
  } while (0)

  // prologue: S(0), e1(0), S(1) in ROTATED space -> 6 VMEM outstanding
  STG(phase, 0);
  float e1n[2], e1c[2];
  #pragma unroll
  for (int j = 0; j < 2; j++) e1n[j] = E1t[phase * 8192 + nrow[j]];
  STG((1 + phase) & 63, 1);

  const f32x4 Z4 = (f32x4){0.f, 0.f, 0.f, 0.f};

  #pragma unroll 1
  for (int kt = 0; kt < 64; ++kt) {
    const int cb = kt % 3;
    const int sb = (kt + 2) % 3;
    const int tn  = (kt + 1 > 63) ? 63 : kt + 1;       // logical (tail: dummy)
    const int ts  = (kt + 2 > 63) ? 63 : kt + 2;
    const int tnp = (tn + phase) & 63;                 // physical tile indices
    const int tsp = (ts + phase) & 63;

    asm volatile("s_waitcnt vmcnt(4)" ::: "memory");   // S(kt) landed
    __builtin_amdgcn_s_barrier();                      // publish tile kt

    bf16x8 a[4][2];
    #pragma unroll
    for (int i = 0; i < 4; i++)
      #pragma unroll
      for (int ks = 0; ks < 2; ks++)
        a[i][ks] = *(const bf16x8*)&As[cb][(i * 16 + l16) * 64 +
                                          (((ks * 4 + quad) ^ sw) * 8)];

    #pragma unroll
    for (int j = 0; j < 2; j++) e1c[j] = e1n[j];
    #pragma unroll
    for (int j = 0; j < 2; j++) e1n[j] = E1t[tnp * 8192 + nrow[j]]; // +2 VMEM
    STG(tsp, sb);                                                   // +2 VMEM

    __builtin_amdgcn_s_setprio(1);
    #pragma unroll
    for (int j = 0; j < 2; j++) {
      const f32x4 s4 = (f32x4){e1c[j], e1c[j], e1c[j], e1c[j]};
      #pragma unroll
      for (int i = 0; i < 4; i++) {
        f32x4 P = __builtin_amdgcn_mfma_f32_16x16x32_bf16(a[i][0], e2f[0][j], Z4, 0, 0, 0);
        P = __builtin_amdgcn_mfma_f32_16x16x32_bf16(a[i][1], e2f[1][j], P, 0, 0, 0);
        acc[i][j] += s4 * P;                           // f32 fold of e1
      }
    }
    __builtin_amdgcn_s_setprio(0);
    // no bottom barrier: restage target (kt+2)%3 last read at kt-1, ordered
    // by this kt's top barrier.
  }

  asm volatile("s_waitcnt vmcnt(0)" ::: "memory");     // drain tail dummies

  // epilogue: C/D layout col=lane&15, row=quad*4+reg
  #pragma unroll
  for (int i = 0; i < 4; i++) {
    #pragma unroll
    for (int r = 0; r < 4; r++) {
      const int brow = m0 + i * 16 + quad * 4 + r;
      float* crow = C + (size_t)brow * 8192 + n0 + wn + l16;
      #pragma unroll
      for (int j = 0; j < 2; j++) crow[j * 16] = acc[i][j][r];
    }
  }
  #undef STG
}

// ---------------- k3: row-normalize d_out (1024 rows of 8192) ----------------
__global__ __launch_bounds__(256) void norm_kernel(float* __restrict__ out) {
  const int b = blockIdx.x;
  const int t = threadIdx.x;
  const int lane = t & 63, wave = t >> 6;
  __shared__ float red[4];

  float4* row = (float4*)(out + (size_t)b * 8192);   // 2048 float4
  float4 v[8];
  float s = 0.0f;
  #pragma unroll
  for (int q = 0; q < 8; q++) {
    v[q] = row[q * 256 + t];
    s += (v[q].x + v[q].y) + (v[q].z + v[q].w);
  }
  float ws = wave_sum(s);
  if (lane == 0) red[wave] = ws;
  __syncthreads();
  float tot = (red[0] + red[1]) + (red[2] + red[3]);
  float inv = 1.0f / tot;
  #pragma unroll
  for (int q = 0; q < 8; q++) {
    v[q].x *= inv; v[q].y *= inv; v[q].z *= inv; v[q].w *= inv;
    row[q * 256 + t] = v[q];
  }
}

// ---------------------------------------------------------------------------
extern "C" void kernel_launch(void* const* d_in, const int* in_sizes, int n_in,
                              void* d_out, int out_size, void* d_ws, size_t ws_size,
                              hipStream_t stream) {
  const float* freq    = (const float*)d_in[0];   // 1024*4096
  const float* kparams = (const float*)d_in[1];   // 8192*4*6
  const float* temp    = (const float*)d_in[2];   // 1
  // d_in[3] = kmer_idcs (recomputed analytically in-kernel)

  float* out = (float*)d_out;                     // 1024*8192 f32

  short* freqb = (short*)d_ws;                    // 1024*4096 bf16 = 8 MiB
  float* E1t   = (float*)(freqb + (size_t)1024 * 4096);  // 64*8192 f32 = 2 MiB
  float* E2    = E1t + (size_t)64 * 8192;                // 8192*64 f32 = 2 MiB

  prep_kernel<<<6144, 256, 0, stream>>>(freq, freqb, kparams, temp, E1t, E2);
  gemm_kernel<<<dim3(64, 16), 256, 0, stream>>>(freqb, E1t, E2, out);
  norm_kernel<<<1024, 256, 0, stream>>>(out);
}